// Round 6
// baseline (529.524 us; speedup 1.0000x reference)
//
#include <hip/hip_runtime.h>
#include <math.h>

constexpr int H_ = 1024;
constexpr int I_ = 2816;
constexpr int E_ = 8;
constexpr int T_ = 1024;
constexpr int SLAB = 256;   // max tokens per expert slab

typedef __bf16 bf16x8 __attribute__((ext_vector_type(8)));
typedef float f32x4 __attribute__((ext_vector_type(4)));

__device__ __forceinline__ ushort f2bf(float f) {
    uint32_t u = __float_as_uint(f);
    u += 0x7fff + ((u >> 16) & 1);   // RNE
    return (ushort)(u >> 16);
}
__device__ __forceinline__ uint pack2(float lo, float hi) {
    return (uint)f2bf(lo) | ((uint)f2bf(hi) << 16);
}
__device__ __forceinline__ bf16x8 cvt8(float4 a, float4 b) {
    uint4 p = make_uint4(pack2(a.x, a.y), pack2(a.z, a.w), pack2(b.x, b.y), pack2(b.z, b.w));
    return __builtin_bit_cast(bf16x8, p);
}

// ws: int counts[8]; int tlist[8*1024]; ushort xg[8*256*1024]; ushort act[8*256*2816]

__global__ __launch_bounds__(64) void router_kernel(const float* __restrict__ hidden,
                                                    const float* __restrict__ rw,
                                                    int* __restrict__ counts,
                                                    int* __restrict__ tlist) {
    const int t = blockIdx.x;
    const int lane = threadIdx.x;
    const float4* x = (const float4*)(hidden + (size_t)t * H_) + lane;
    float4 v[4];
#pragma unroll
    for (int j = 0; j < 4; j++) v[j] = x[j * 64];
    float acc[E_];
#pragma unroll
    for (int e = 0; e < E_; e++) {
        const float4* r = (const float4*)(rw + e * H_) + lane;
        float a = 0.f;
#pragma unroll
        for (int j = 0; j < 4; j++) {
            float4 rv = r[j * 64];
            a += v[j].x * rv.x + v[j].y * rv.y + v[j].z * rv.z + v[j].w * rv.w;
        }
        acc[e] = a;
    }
#pragma unroll
    for (int e = 0; e < E_; e++) {
#pragma unroll
        for (int off = 32; off >= 1; off >>= 1)
            acc[e] += __shfl_xor(acc[e], off, 64);
    }
    if (lane == 0) {
        int best = 0;
        float bv = acc[0];
#pragma unroll
        for (int e = 1; e < E_; e++)
            if (acc[e] > bv) { bv = acc[e]; best = e; }   // strict > : first max wins
        int pos = atomicAdd(&counts[best], 1);
        if (pos < T_) tlist[best * T_ + pos] = t;
    }
}

__global__ __launch_bounds__(64) void gather_kernel(const float* __restrict__ hidden,
                                                    const int* __restrict__ counts,
                                                    const int* __restrict__ tlist,
                                                    ushort* __restrict__ xg) {
    const int r = blockIdx.x;            // 0..2047
    const int e = r >> 8, slot = r & 255;
    int cnt = counts[e]; if (cnt > SLAB) cnt = SLAB;
    const int limit = ((cnt + 127) >> 7) << 7;
    if (slot >= limit) return;
    ushort* dst = xg + (size_t)r * H_;
    const int lane = threadIdx.x;
    if (slot < cnt) {
        const int tok = tlist[e * T_ + slot];
        const float4* src = (const float4*)(hidden + (size_t)tok * H_) + lane;
        uint2* d = (uint2*)dst + lane;
#pragma unroll
        for (int j = 0; j < 4; j++) {
            float4 v = src[j * 64];
            d[j * 64] = make_uint2(pack2(v.x, v.y), pack2(v.z, v.w));
        }
    } else {
        uint4* d = (uint4*)dst + lane;
        d[0]  = make_uint4(0u, 0u, 0u, 0u);
        d[64] = make_uint4(0u, 0u, 0u, 0u);
    }
}

// ---------------- Phase A: one wave per (expert, 16-wide I tile). ----------------
// M=128 tokens per pass, no LDS, no barriers. A/B fragments loaded directly in
// MFMA layout: A row=l15 k=quad*8 (bf16 slab); B row=i0+l15 (fp32 -> cvt).
__global__ __launch_bounds__(64) void gateup_kernel(const ushort* __restrict__ xg,
                                                    const float* __restrict__ gate_w,
                                                    const float* __restrict__ up_w,
                                                    const int* __restrict__ counts,
                                                    ushort* __restrict__ act) {
    const int e  = blockIdx.y;
    const int i0 = blockIdx.x * 16;
    int cnt = counts[e]; if (cnt > SLAB) cnt = SLAB;
    const int mtiles = (cnt + 127) >> 7;
    const int lane = threadIdx.x;
    const int quad = lane >> 4, l15 = lane & 15;

    const float* gw = gate_w + (size_t)e * I_ * H_ + (size_t)(i0 + l15) * H_ + quad * 8;
    const float* uw = up_w   + (size_t)e * I_ * H_ + (size_t)(i0 + l15) * H_ + quad * 8;

    for (int mt = 0; mt < mtiles; mt++) {
        const ushort* xb = xg + ((size_t)e * SLAB + mt * 128 + l15) * H_ + quad * 8;

        f32x4 accg[8], accu[8];
#pragma unroll
        for (int mi = 0; mi < 8; mi++) {
            accg[mi] = (f32x4){0.f, 0.f, 0.f, 0.f};
            accu[mi] = (f32x4){0.f, 0.f, 0.f, 0.f};
        }

#pragma unroll 4
        for (int k = 0; k < H_; k += 32) {
            float4 g0 = *(const float4*)(gw + k);
            float4 g1 = *(const float4*)(gw + k + 4);
            float4 u0 = *(const float4*)(uw + k);
            float4 u1 = *(const float4*)(uw + k + 4);
            bf16x8 a[8];
#pragma unroll
            for (int mi = 0; mi < 8; mi++)
                a[mi] = *(const bf16x8*)(xb + (size_t)mi * 16 * H_ + k);
            bf16x8 bg = cvt8(g0, g1);
            bf16x8 bu = cvt8(u0, u1);
#pragma unroll
            for (int mi = 0; mi < 8; mi++) {
                accg[mi] = __builtin_amdgcn_mfma_f32_16x16x32_bf16(a[mi], bg, accg[mi], 0, 0, 0);
                accu[mi] = __builtin_amdgcn_mfma_f32_16x16x32_bf16(a[mi], bu, accu[mi], 0, 0, 0);
            }
        }

        // D: col = l15 (i), row = quad*4 + r (slot). Write act (incl. zero pads).
#pragma unroll
        for (int mi = 0; mi < 8; mi++) {
#pragma unroll
            for (int r = 0; r < 4; r++) {
                int slot = mt * 128 + mi * 16 + quad * 4 + r;
                float g = accg[mi][r], u = accu[mi][r];
                float s = g / (1.f + __expf(-g)) * u;
                act[((size_t)e * SLAB + slot) * I_ + i0 + l15] = f2bf(s);
            }
        }
    }
}

// ---------------- Phase B: one wave per (expert, 16-wide H tile, K-half). ----------------
// K split in 2 (z dim); partial sums combined via atomicAdd into zero-initialized out.
__global__ __launch_bounds__(64) void down_kernel(const ushort* __restrict__ act,
                                                  const float* __restrict__ down_w,
                                                  const int* __restrict__ counts,
                                                  const int* __restrict__ tlist,
                                                  float* __restrict__ out) {
    const int e  = blockIdx.y;
    const int h0 = blockIdx.x * 16;
    const int ks = blockIdx.z * (I_ / 2);       // 0 or 1408
    int cnt = counts[e]; if (cnt > SLAB) cnt = SLAB;
    const int mtiles = (cnt + 127) >> 7;
    const int lane = threadIdx.x;
    const int quad = lane >> 4, l15 = lane & 15;

    const float* dw = down_w + (size_t)e * H_ * I_ + (size_t)(h0 + l15) * I_ + quad * 8;

    for (int mt = 0; mt < mtiles; mt++) {
        const ushort* ab = act + ((size_t)e * SLAB + mt * 128 + l15) * I_ + quad * 8;

        f32x4 acc[8];
#pragma unroll
        for (int mi = 0; mi < 8; mi++) acc[mi] = (f32x4){0.f, 0.f, 0.f, 0.f};

#pragma unroll 4
        for (int k = 0; k < I_ / 2; k += 32) {
            float4 d0 = *(const float4*)(dw + ks + k);
            float4 d1 = *(const float4*)(dw + ks + k + 4);
            bf16x8 a[8];
#pragma unroll
            for (int mi = 0; mi < 8; mi++)
                a[mi] = *(const bf16x8*)(ab + (size_t)mi * 16 * I_ + ks + k);
            bf16x8 bd = cvt8(d0, d1);
#pragma unroll
            for (int mi = 0; mi < 8; mi++)
                acc[mi] = __builtin_amdgcn_mfma_f32_16x16x32_bf16(a[mi], bd, acc[mi], 0, 0, 0);
        }

#pragma unroll
        for (int mi = 0; mi < 8; mi++) {
#pragma unroll
            for (int r = 0; r < 4; r++) {
                int slot = mt * 128 + mi * 16 + quad * 4 + r;
                if (slot < cnt) {
                    int tok = tlist[e * T_ + slot];
                    atomicAdd(&out[(size_t)tok * H_ + h0 + l15], acc[mi][r]);
                }
            }
        }
    }
}

extern "C" void kernel_launch(void* const* d_in, const int* in_sizes, int n_in,
                              void* d_out, int out_size, void* d_ws, size_t ws_size,
                              hipStream_t stream) {
    const float* hidden = (const float*)d_in[0];
    const float* rw     = (const float*)d_in[1];
    const float* gate_w = (const float*)d_in[2];
    const float* up_w   = (const float*)d_in[3];
    const float* down_w = (const float*)d_in[4];
    float* out = (float*)d_out;

    int* counts = (int*)d_ws;
    int* tlist  = counts + E_;
    ushort* xg  = (ushort*)(tlist + E_ * T_);            // 4 MB
    ushort* act = xg + (size_t)E_ * SLAB * H_;           // 11.5 MB

    hipMemsetAsync(counts, 0, E_ * sizeof(int), stream);
    hipMemsetAsync(out, 0, (size_t)out_size * sizeof(float), stream);
    hipLaunchKernelGGL(router_kernel, dim3(T_), dim3(64), 0, stream, hidden, rw, counts, tlist);
    hipLaunchKernelGGL(gather_kernel, dim3(E_ * SLAB), dim3(64), 0, stream, hidden, counts, tlist, xg);
    hipLaunchKernelGGL(gateup_kernel, dim3(I_ / 16, E_), dim3(64), 0, stream,
                       xg, gate_w, up_w, counts, act);
    hipLaunchKernelGGL(down_kernel, dim3(H_ / 16, E_, 2), dim3(64), 0, stream,
                       act, down_w, counts, tlist, out);
}